// Round 5
// baseline (215.418 us; speedup 1.0000x reference)
//
#include <hip/hip_runtime.h>

#define N_NODES 150000
#define N_EDGES 2400000
#define F_IN    22
#define HID     32
#define N_CLS   6
#define BN_EPS  1e-5f

#define BSHIFT  7
#define BMASK   127
#define NB      ((N_NODES + BMASK) >> BSHIFT)       // 1172 buckets of 128 nodes
#define CHUNK   4096
#define EPT     (CHUNK / 256)                       // 16 edges per thread
#define NBLK_BIN ((N_EDGES + CHUNK - 1) / CHUNK)    // 586 blocks
#define CHUNK_H 8192
#define NBLK_H  ((N_EDGES + CHUNK_H - 1) / CHUNK_H) // 293 hist blocks
#define NBLK_EMB ((N_NODES + 255) / 256)            // 586 embed blocks

// ---------------------------------------------------------------------------
// K0 (fused): blocks [0,NBLK_EMB) -> per-node h = relu(x@W_emb+b_emb)@W_gcn
//             blocks [NBLK_EMB, NBLK_EMB+NBLK_H) -> bucket histogram of dst
// ---------------------------------------------------------------------------
__global__ void embed_hist_kernel(const float* __restrict__ x,
                                  const float* __restrict__ W_emb,
                                  const float* __restrict__ b_emb,
                                  const float* __restrict__ W_gcn,
                                  float* __restrict__ h,
                                  const int* __restrict__ dst,
                                  int* __restrict__ bcnt) {
    if (blockIdx.x < NBLK_EMB) {
        __shared__ float sWe[F_IN * HID];
        __shared__ float sbe[HID];
        __shared__ float sWg[HID * HID];
        for (int t = threadIdx.x; t < F_IN * HID; t += blockDim.x) sWe[t] = W_emb[t];
        if (threadIdx.x < HID) sbe[threadIdx.x] = b_emb[threadIdx.x];
        for (int t = threadIdx.x; t < HID * HID; t += blockDim.x) sWg[t] = W_gcn[t];
        __syncthreads();

        int i = blockIdx.x * blockDim.x + threadIdx.x;
        if (i >= N_NODES) return;

        float xi[F_IN];
#pragma unroll
        for (int f = 0; f < F_IN; ++f) xi[f] = x[(size_t)i * F_IN + f];

        float h1[HID];
#pragma unroll
        for (int j = 0; j < HID; ++j) {
            float acc = sbe[j];
#pragma unroll
            for (int f = 0; f < F_IN; ++f) acc = fmaf(xi[f], sWe[f * HID + j], acc);
            h1[j] = fmaxf(acc, 0.0f);
        }
#pragma unroll
        for (int j = 0; j < HID; ++j) {
            float acc = 0.0f;
#pragma unroll
            for (int f = 0; f < HID; ++f) acc = fmaf(h1[f], sWg[f * HID + j], acc);
            h[(size_t)i * HID + j] = acc;
        }
    } else {
        __shared__ int hloc[NB];
        for (int t = threadIdx.x; t < NB; t += 256) hloc[t] = 0;
        __syncthreads();
        int base = (blockIdx.x - NBLK_EMB) * CHUNK_H;
        int end = base + CHUNK_H; if (end > N_EDGES) end = N_EDGES;
        for (int i = base + threadIdx.x; i < end; i += 256)
            atomicAdd(&hloc[dst[i] >> BSHIFT], 1);
        __syncthreads();
        for (int t = threadIdx.x; t < NB; t += 256)
            if (hloc[t]) atomicAdd(&bcnt[t], hloc[t]);
    }
}

// ---------------------------------------------------------------------------
// K1: single-block exclusive scan of NB (=1172) bucket counts -> boff, bcur
//     1024 threads, 2 elements each (pair-sum + Hillis-Steele on pairs)
// ---------------------------------------------------------------------------
__global__ void bucket_scan_kernel(const int* __restrict__ bcnt,
                                   int* __restrict__ boff,
                                   int* __restrict__ bcur) {
    __shared__ int q[1024];
    int t = threadIdx.x;
    int i0 = 2 * t, i1 = 2 * t + 1;
    int a0 = (i0 < NB) ? bcnt[i0] : 0;
    int a1 = (i1 < NB) ? bcnt[i1] : 0;
    q[t] = a0 + a1;
    __syncthreads();
#pragma unroll
    for (int o = 1; o < 1024; o <<= 1) {
        int v = (t >= o) ? q[t - o] : 0;
        __syncthreads();
        q[t] += v;                 // inclusive pair-sum scan
        __syncthreads();
    }
    int incl1 = q[t];
    int incl0 = incl1 - a1;
    int e0 = incl0 - a0;
    int e1 = incl1 - a1;
    if (i0 < NB) { boff[i0] = e0; bcur[i0] = e0; }
    if (i1 < NB) { boff[i1] = e1; bcur[i1] = e1; }
    if (t == 1023) boff[NB] = q[1023];   // == N_EDGES
}

// ---------------------------------------------------------------------------
// K2: binned append. Per block: LDS hist of its chunk -> one global atomic per
//     touched bucket to reserve a range -> packed writes.
//     packed = (dst & 127) << 24 | src   (src < 2^24)
// ---------------------------------------------------------------------------
__global__ void bin_edges_kernel(const int* __restrict__ src,
                                 const int* __restrict__ dst,
                                 int* __restrict__ bcur,
                                 unsigned int* __restrict__ binned) {
    __shared__ int hloc[NB];
    __shared__ int base[NB];
    __shared__ int lcur[NB];
    for (int t = threadIdx.x; t < NB; t += 256) hloc[t] = 0;
    __syncthreads();

    int cbase = blockIdx.x * CHUNK;
    int dreg[EPT];
#pragma unroll
    for (int k = 0; k < EPT; ++k) {
        int i = cbase + threadIdx.x + k * 256;
        int d = -1;
        if (i < N_EDGES) {
            d = dst[i];
            atomicAdd(&hloc[d >> BSHIFT], 1);
        }
        dreg[k] = d;
    }
    __syncthreads();
    for (int t = threadIdx.x; t < NB; t += 256) {
        int c = hloc[t];
        base[t] = c ? atomicAdd(&bcur[t], c) : 0;
        lcur[t] = 0;
    }
    __syncthreads();
#pragma unroll
    for (int k = 0; k < EPT; ++k) {
        int d = dreg[k];
        if (d < 0) continue;
        int i = cbase + threadIdx.x + k * 256;
        int b = d >> BSHIFT;
        int r = atomicAdd(&lcur[b], 1);
        binned[base[b] + r] = ((unsigned)(d & BMASK) << 24) | (unsigned)src[i];
    }
}

// ---------------------------------------------------------------------------
// K3: per-bucket local counting sort -> fully dst-sorted sorted_src + off[],
//     plus dis = rsqrt(1+deg) and in-place h *= dis.
//     All heavy writes stay within this bucket's 8 KB window (L2-resident).
// ---------------------------------------------------------------------------
__global__ void bucket_csr_kernel(const int* __restrict__ boff,
                                  const unsigned int* __restrict__ binned,
                                  int* __restrict__ sorted_src,
                                  int* __restrict__ off,
                                  float* __restrict__ h,
                                  float* __restrict__ dis) {
    __shared__ int s_cnt[256];
    __shared__ int s_scan[256];
    __shared__ int s_cur[256];
    __shared__ float dl[128];
    int b = blockIdx.x;
    int t = threadIdx.x;
    int s0 = boff[b], s1 = boff[b + 1];
    int nbase = b << BSHIFT;
    int nnode = N_NODES - nbase; if (nnode > 128) nnode = 128;

    s_cnt[t] = 0;
    __syncthreads();
    for (int k = s0 + t; k < s1; k += 256)
        atomicAdd(&s_cnt[binned[k] >> 24], 1);
    __syncthreads();

    int v = s_cnt[t];
    s_scan[t] = v;
    __syncthreads();
#pragma unroll
    for (int o = 1; o < 256; o <<= 1) {
        int u = (t >= o) ? s_scan[t - o] : 0;
        __syncthreads();
        s_scan[t] += u;            // inclusive
        __syncthreads();
    }
    int excl = s_scan[t] - v;
    s_cur[t] = excl;
    if (t < nnode) {
        off[nbase + t] = s0 + excl;
        float d = rsqrtf(1.0f + (float)v);
        dl[t] = d;
        dis[nbase + t] = d;
    }
    if (b == NB - 1 && t == 0) off[N_NODES] = N_EDGES;
    __syncthreads();

    // scale this bucket's h rows in place: hs = h * dis
    float4* hv = reinterpret_cast<float4*>(h) + (size_t)nbase * 8;
    for (int tt = t; tt < nnode * 8; tt += 256) {
        float4 w = hv[tt];
        float d = dl[tt >> 3];
        w.x *= d; w.y *= d; w.z *= d; w.w *= d;
        hv[tt] = w;
    }

    // scatter to node-sorted order (writes stay inside [s0,s1) = 8 KB window)
    for (int k = s0 + t; k < s1; k += 256) {
        unsigned p = binned[k];
        int n = (int)(p >> 24);
        int r = atomicAdd(&s_cur[n], 1);
        sorted_src[s0 + r] = (int)(p & 0xFFFFFFu);
    }
}

// ---------------------------------------------------------------------------
// K4: per-node aggregation, 8 threads/node, coalesced float4 gathers, no
//     atomics.  agg[n] = (hs[n] + sum_{in(n)} hs[src]) * dis[n]
// ---------------------------------------------------------------------------
__global__ void aggregate_kernel(const int* __restrict__ off,
                                 const int* __restrict__ sorted_src,
                                 const float* __restrict__ hs,
                                 const float* __restrict__ dis,
                                 float* __restrict__ agg) {
    int t = blockIdx.x * blockDim.x + threadIdx.x;
    int node = t >> 3;
    int c = t & 7;
    if (node >= N_NODES) return;

    const float4* hrow = reinterpret_cast<const float4*>(hs);
    float4 acc = hrow[(size_t)node * 8 + c];          // self-loop term
    int b = off[node], e = off[node + 1];
    for (int k = b; k < e; ++k) {
        int s = sorted_src[k];
        float4 v = hrow[(size_t)s * 8 + c];
        acc.x += v.x; acc.y += v.y; acc.z += v.z; acc.w += v.w;
    }
    float d = dis[node];
    acc.x *= d; acc.y *= d; acc.z *= d; acc.w *= d;
    reinterpret_cast<float4*>(agg)[(size_t)node * 8 + c] = acc;
}

// ---------------------------------------------------------------------------
// K5: per-feature sum / sumsq over agg rows (stats[0..31]=sum, [32..63]=sumsq)
// ---------------------------------------------------------------------------
__global__ void stats_kernel(const float* __restrict__ agg,
                             float* __restrict__ stats) {
    float s = 0.0f, sq = 0.0f;
    int idx = blockIdx.x * blockDim.x + threadIdx.x;
    int stride = gridDim.x * blockDim.x;
    for (; idx < N_NODES * HID; idx += stride) {
        float v = agg[idx];
        s += v;
        sq = fmaf(v, v, sq);
    }
    __shared__ float ss[256];
    __shared__ float ssq[256];
    ss[threadIdx.x] = s;
    ssq[threadIdx.x] = sq;
    __syncthreads();
    if (threadIdx.x < 32) {
        float ts = 0.0f, tq = 0.0f;
#pragma unroll
        for (int g = 0; g < 256; g += 32) {
            ts += ss[g + threadIdx.x];
            tq += ssq[g + threadIdx.x];
        }
        atomicAdd(&stats[threadIdx.x], ts);
        atomicAdd(&stats[32 + threadIdx.x], tq);
    }
}

// ---------------------------------------------------------------------------
// K6: out = relu(agg*A + B) @ W_cls + b_cls   (BN fold computed per-block)
// ---------------------------------------------------------------------------
__global__ void cls_kernel(const float* __restrict__ agg,
                           const float* __restrict__ stats,
                           const float* __restrict__ gamma,
                           const float* __restrict__ beta,
                           const float* __restrict__ W_cls,
                           const float* __restrict__ b_cls,
                           float* __restrict__ out) {
    __shared__ float sA[HID];
    __shared__ float sB[HID];
    __shared__ float sW[HID * N_CLS];
    __shared__ float sb[N_CLS];
    if (threadIdx.x < HID) {
        const float invN = 1.0f / (float)N_NODES;
        float mean = stats[threadIdx.x] * invN;
        float var = stats[32 + threadIdx.x] * invN - mean * mean;
        float inv = rsqrtf(var + BN_EPS);
        float A = gamma[threadIdx.x] * inv;
        sA[threadIdx.x] = A;
        sB[threadIdx.x] = beta[threadIdx.x] - mean * A;
    }
    for (int t = threadIdx.x; t < HID * N_CLS; t += blockDim.x) sW[t] = W_cls[t];
    if (threadIdx.x < N_CLS) sb[threadIdx.x] = b_cls[threadIdx.x];
    __syncthreads();

    int i = blockIdx.x * blockDim.x + threadIdx.x;
    if (i >= N_NODES) return;

    float acc[N_CLS];
#pragma unroll
    for (int c = 0; c < N_CLS; ++c) acc[c] = sb[c];
#pragma unroll
    for (int f = 0; f < HID; ++f) {
        float t = fmaxf(fmaf(agg[(size_t)i * HID + f], sA[f], sB[f]), 0.0f);
#pragma unroll
        for (int c = 0; c < N_CLS; ++c) acc[c] = fmaf(t, sW[f * N_CLS + c], acc[c]);
    }
#pragma unroll
    for (int c = 0; c < N_CLS; ++c) out[(size_t)i * N_CLS + c] = acc[c];
}

// ---------------------------------------------------------------------------
extern "C" void kernel_launch(void* const* d_in, const int* in_sizes, int n_in,
                              void* d_out, int out_size, void* d_ws, size_t ws_size,
                              hipStream_t stream) {
    const float* x     = (const float*)d_in[0];
    const int*   edge  = (const int*)d_in[1];   // [2, E] int32
    const float* W_emb = (const float*)d_in[2];
    const float* b_emb = (const float*)d_in[3];
    const float* W_gcn = (const float*)d_in[4];
    // d_in[5] = b_gcn: per-feature constant, cancels exactly in BatchNorm -> skip
    const float* gamma = (const float*)d_in[6];
    const float* beta  = (const float*)d_in[7];
    const float* W_cls = (const float*)d_in[8];
    const float* b_cls = (const float*)d_in[9];
    float* out = (float*)d_out;

    // workspace layout (~59 MB)
    float*        h          = (float*)d_ws;                    // N*HID (scaled in place)
    float*        agg        = h + (size_t)N_NODES * HID;       // N*HID
    float*        dis        = agg + (size_t)N_NODES * HID;     // N
    int*          off        = (int*)(dis + N_NODES);           // N+1
    int*          bcnt       = off + N_NODES + 1;               // NB
    int*          boff       = bcnt + NB;                       // NB+1
    int*          bcur       = boff + NB + 1;                   // NB
    unsigned int* binned     = (unsigned int*)(bcur + NB);      // E
    int*          sorted_src = (int*)(binned + N_EDGES);        // E
    float*        stats      = (float*)(sorted_src + N_EDGES);  // 64

    hipMemsetAsync(bcnt, 0, NB * sizeof(int), stream);
    hipMemsetAsync(stats, 0, 64 * sizeof(float), stream);

    const int* src = edge;
    const int* dst = edge + N_EDGES;

    embed_hist_kernel<<<NBLK_EMB + NBLK_H, 256, 0, stream>>>(x, W_emb, b_emb, W_gcn,
                                                             h, dst, bcnt);
    bucket_scan_kernel<<<1, 1024, 0, stream>>>(bcnt, boff, bcur);
    bin_edges_kernel<<<NBLK_BIN, 256, 0, stream>>>(src, dst, bcur, binned);
    bucket_csr_kernel<<<NB, 256, 0, stream>>>(boff, binned, sorted_src, off, h, dis);
    aggregate_kernel<<<(N_NODES * 8 + 255) / 256, 256, 0, stream>>>(off, sorted_src,
                                                                    h, dis, agg);
    stats_kernel<<<1024, 256, 0, stream>>>(agg, stats);
    cls_kernel<<<(N_NODES + 255) / 256, 256, 0, stream>>>(agg, stats, gamma, beta,
                                                          W_cls, b_cls, out);
}

// Round 6
// 194.618 us; speedup vs baseline: 1.1069x; 1.1069x over previous
//
#include <hip/hip_runtime.h>

#define N_NODES 150000
#define N_EDGES 2400000
#define F_IN    22
#define HID     32
#define N_CLS   6
#define BN_EPS  1e-5f

#define BSHIFT  8
#define BMASK   255
#define NB      ((N_NODES + BMASK) >> BSHIFT)       // 586 buckets of 256 nodes
#define CHUNK   8192                                // edges per bin block
#define NBLK_BIN ((N_EDGES + CHUNK - 1) / CHUNK)    // 293 blocks
#define CHUNK_H 8192
#define NBLK_H  ((N_EDGES + CHUNK_H - 1) / CHUNK_H) // 293 hist blocks
#define NBLK_EMB ((N_NODES + 255) / 256)            // 586 embed blocks

// ---------------------------------------------------------------------------
// K0 (fused): blocks [0,NBLK_EMB) -> per-node h = relu(x@W_emb+b_emb)@W_gcn
//             blocks [NBLK_EMB, NBLK_EMB+NBLK_H) -> bucket histogram of dst
// ---------------------------------------------------------------------------
__global__ void embed_hist_kernel(const float* __restrict__ x,
                                  const float* __restrict__ W_emb,
                                  const float* __restrict__ b_emb,
                                  const float* __restrict__ W_gcn,
                                  float* __restrict__ h,
                                  const int* __restrict__ dst,
                                  int* __restrict__ bcnt) {
    if (blockIdx.x < NBLK_EMB) {
        __shared__ float sWe[F_IN * HID];
        __shared__ float sbe[HID];
        __shared__ float sWg[HID * HID];
        for (int t = threadIdx.x; t < F_IN * HID; t += blockDim.x) sWe[t] = W_emb[t];
        if (threadIdx.x < HID) sbe[threadIdx.x] = b_emb[threadIdx.x];
        for (int t = threadIdx.x; t < HID * HID; t += blockDim.x) sWg[t] = W_gcn[t];
        __syncthreads();

        int i = blockIdx.x * blockDim.x + threadIdx.x;
        if (i >= N_NODES) return;

        float xi[F_IN];
#pragma unroll
        for (int f = 0; f < F_IN; ++f) xi[f] = x[(size_t)i * F_IN + f];

        float h1[HID];
#pragma unroll
        for (int j = 0; j < HID; ++j) {
            float acc = sbe[j];
#pragma unroll
            for (int f = 0; f < F_IN; ++f) acc = fmaf(xi[f], sWe[f * HID + j], acc);
            h1[j] = fmaxf(acc, 0.0f);
        }
#pragma unroll
        for (int j = 0; j < HID; ++j) {
            float acc = 0.0f;
#pragma unroll
            for (int f = 0; f < HID; ++f) acc = fmaf(h1[f], sWg[f * HID + j], acc);
            h[(size_t)i * HID + j] = acc;
        }
    } else {
        __shared__ int hloc[NB];
        for (int t = threadIdx.x; t < NB; t += 256) hloc[t] = 0;
        __syncthreads();
        int base = (blockIdx.x - NBLK_EMB) * CHUNK_H;
        int end = base + CHUNK_H; if (end > N_EDGES) end = N_EDGES;
        for (int i = base + threadIdx.x; i < end; i += 256)
            atomicAdd(&hloc[dst[i] >> BSHIFT], 1);
        __syncthreads();
        for (int t = threadIdx.x; t < NB; t += 256)
            if (hloc[t]) atomicAdd(&bcnt[t], hloc[t]);
    }
}

// ---------------------------------------------------------------------------
// K1: single-block exclusive scan of NB (=586) bucket counts -> boff, bcur
// ---------------------------------------------------------------------------
__global__ void bucket_scan_kernel(const int* __restrict__ bcnt,
                                   int* __restrict__ boff,
                                   int* __restrict__ bcur) {
    __shared__ int s[1024];
    int t = threadIdx.x;
    int v0 = (t < NB) ? bcnt[t] : 0;
    s[t] = v0;
    __syncthreads();
#pragma unroll
    for (int o = 1; o < 1024; o <<= 1) {
        int v = (t >= o) ? s[t - o] : 0;
        __syncthreads();
        s[t] += v;                 // inclusive
        __syncthreads();
    }
    if (t < NB) {
        int e = s[t] - v0;         // exclusive
        boff[t] = e;
        bcur[t] = e;
    }
    if (t == NB - 1) boff[NB] = s[t];   // == N_EDGES
}

// ---------------------------------------------------------------------------
// K2: binned append, 512 threads. Per block: LDS hist of its 8192-edge chunk
//     -> one global atomic per touched bucket to reserve a range -> packed
//     writes (~56 B runs per (block,bucket)).  dst re-read from L2 in pass 2
//     instead of register-caching (saves 32 VGPRs).
//     packed = (dst & 255) << 24 | src   (src < 2^24)
// ---------------------------------------------------------------------------
__global__ void bin_edges_kernel(const int* __restrict__ src,
                                 const int* __restrict__ dst,
                                 int* __restrict__ bcur,
                                 unsigned int* __restrict__ binned) {
    __shared__ int hloc[NB];
    __shared__ int base[NB];
    __shared__ int lcur[NB];
    for (int t = threadIdx.x; t < NB; t += 512) hloc[t] = 0;
    __syncthreads();

    int cbase = blockIdx.x * CHUNK;
    int cend = cbase + CHUNK; if (cend > N_EDGES) cend = N_EDGES;
    for (int i = cbase + threadIdx.x; i < cend; i += 512)
        atomicAdd(&hloc[dst[i] >> BSHIFT], 1);
    __syncthreads();
    for (int t = threadIdx.x; t < NB; t += 512) {
        int c = hloc[t];
        base[t] = c ? atomicAdd(&bcur[t], c) : 0;
        lcur[t] = 0;
    }
    __syncthreads();
    for (int i = cbase + threadIdx.x; i < cend; i += 512) {
        int d = dst[i];
        int b = d >> BSHIFT;
        int r = atomicAdd(&lcur[b], 1);
        binned[base[b] + r] = ((unsigned)(d & BMASK) << 24) | (unsigned)src[i];
    }
}

// ---------------------------------------------------------------------------
// K3: per-bucket local counting sort -> fully dst-sorted sorted_src + off[],
//     plus dis = rsqrt(1+deg) and in-place h *= dis.
//     All heavy writes stay within this bucket's 16 KB window (L2-resident).
// ---------------------------------------------------------------------------
__global__ void bucket_csr_kernel(const int* __restrict__ boff,
                                  const unsigned int* __restrict__ binned,
                                  int* __restrict__ sorted_src,
                                  int* __restrict__ off,
                                  float* __restrict__ h,
                                  float* __restrict__ dis) {
    __shared__ int s_cnt[256];
    __shared__ int s_scan[256];
    __shared__ int s_cur[256];
    __shared__ float dl[256];
    int b = blockIdx.x;
    int t = threadIdx.x;
    int s0 = boff[b], s1 = boff[b + 1];
    int nbase = b << BSHIFT;
    int nnode = N_NODES - nbase; if (nnode > 256) nnode = 256;

    s_cnt[t] = 0;
    __syncthreads();
    for (int k = s0 + t; k < s1; k += 256)
        atomicAdd(&s_cnt[binned[k] >> 24], 1);
    __syncthreads();

    int v = s_cnt[t];
    s_scan[t] = v;
    __syncthreads();
#pragma unroll
    for (int o = 1; o < 256; o <<= 1) {
        int u = (t >= o) ? s_scan[t - o] : 0;
        __syncthreads();
        s_scan[t] += u;            // inclusive
        __syncthreads();
    }
    int excl = s_scan[t] - v;
    s_cur[t] = excl;
    if (t < nnode) {
        off[nbase + t] = s0 + excl;
        float d = rsqrtf(1.0f + (float)v);
        dl[t] = d;
        dis[nbase + t] = d;
    }
    if (b == NB - 1 && t == 0) off[N_NODES] = N_EDGES;
    __syncthreads();

    // scale this bucket's h rows in place: hs = h * dis
    float4* hv = reinterpret_cast<float4*>(h) + (size_t)nbase * 8;
    for (int tt = t; tt < nnode * 8; tt += 256) {
        float4 w = hv[tt];
        float d = dl[tt >> 3];
        w.x *= d; w.y *= d; w.z *= d; w.w *= d;
        hv[tt] = w;
    }

    // scatter to node-sorted order (writes stay inside [s0,s1) = 16 KB window)
    for (int k = s0 + t; k < s1; k += 256) {
        unsigned p = binned[k];
        int n = (int)(p >> 24);
        int r = atomicAdd(&s_cur[n], 1);
        sorted_src[s0 + r] = (int)(p & 0xFFFFFFu);
    }
}

// ---------------------------------------------------------------------------
// K4: per-node aggregation, 8 threads/node, coalesced float4 gathers, no
//     atomics.  agg[n] = (hs[n] + sum_{in(n)} hs[src]) * dis[n]
// ---------------------------------------------------------------------------
__global__ void aggregate_kernel(const int* __restrict__ off,
                                 const int* __restrict__ sorted_src,
                                 const float* __restrict__ hs,
                                 const float* __restrict__ dis,
                                 float* __restrict__ agg) {
    int t = blockIdx.x * blockDim.x + threadIdx.x;
    int node = t >> 3;
    int c = t & 7;
    if (node >= N_NODES) return;

    const float4* hrow = reinterpret_cast<const float4*>(hs);
    float4 acc = hrow[(size_t)node * 8 + c];          // self-loop term
    int b = off[node], e = off[node + 1];
    for (int k = b; k < e; ++k) {
        int s = sorted_src[k];
        float4 v = hrow[(size_t)s * 8 + c];
        acc.x += v.x; acc.y += v.y; acc.z += v.z; acc.w += v.w;
    }
    float d = dis[node];
    acc.x *= d; acc.y *= d; acc.z *= d; acc.w *= d;
    reinterpret_cast<float4*>(agg)[(size_t)node * 8 + c] = acc;
}

// ---------------------------------------------------------------------------
// K5: per-feature sum / sumsq over agg rows (stats[0..31]=sum, [32..63]=sumsq)
// ---------------------------------------------------------------------------
__global__ void stats_kernel(const float* __restrict__ agg,
                             float* __restrict__ stats) {
    float s = 0.0f, sq = 0.0f;
    int idx = blockIdx.x * blockDim.x + threadIdx.x;
    int stride = gridDim.x * blockDim.x;
    for (; idx < N_NODES * HID; idx += stride) {
        float v = agg[idx];
        s += v;
        sq = fmaf(v, v, sq);
    }
    __shared__ float ss[256];
    __shared__ float ssq[256];
    ss[threadIdx.x] = s;
    ssq[threadIdx.x] = sq;
    __syncthreads();
    if (threadIdx.x < 32) {
        float ts = 0.0f, tq = 0.0f;
#pragma unroll
        for (int g = 0; g < 256; g += 32) {
            ts += ss[g + threadIdx.x];
            tq += ssq[g + threadIdx.x];
        }
        atomicAdd(&stats[threadIdx.x], ts);
        atomicAdd(&stats[32 + threadIdx.x], tq);
    }
}

// ---------------------------------------------------------------------------
// K6: out = relu(agg*A + B) @ W_cls + b_cls   (BN fold computed per-block)
// ---------------------------------------------------------------------------
__global__ void cls_kernel(const float* __restrict__ agg,
                           const float* __restrict__ stats,
                           const float* __restrict__ gamma,
                           const float* __restrict__ beta,
                           const float* __restrict__ W_cls,
                           const float* __restrict__ b_cls,
                           float* __restrict__ out) {
    __shared__ float sA[HID];
    __shared__ float sB[HID];
    __shared__ float sW[HID * N_CLS];
    __shared__ float sb[N_CLS];
    if (threadIdx.x < HID) {
        const float invN = 1.0f / (float)N_NODES;
        float mean = stats[threadIdx.x] * invN;
        float var = stats[32 + threadIdx.x] * invN - mean * mean;
        float inv = rsqrtf(var + BN_EPS);
        float A = gamma[threadIdx.x] * inv;
        sA[threadIdx.x] = A;
        sB[threadIdx.x] = beta[threadIdx.x] - mean * A;
    }
    for (int t = threadIdx.x; t < HID * N_CLS; t += blockDim.x) sW[t] = W_cls[t];
    if (threadIdx.x < N_CLS) sb[threadIdx.x] = b_cls[threadIdx.x];
    __syncthreads();

    int i = blockIdx.x * blockDim.x + threadIdx.x;
    if (i >= N_NODES) return;

    float acc[N_CLS];
#pragma unroll
    for (int c = 0; c < N_CLS; ++c) acc[c] = sb[c];
#pragma unroll
    for (int f = 0; f < HID; ++f) {
        float t = fmaxf(fmaf(agg[(size_t)i * HID + f], sA[f], sB[f]), 0.0f);
#pragma unroll
        for (int c = 0; c < N_CLS; ++c) acc[c] = fmaf(t, sW[f * N_CLS + c], acc[c]);
    }
#pragma unroll
    for (int c = 0; c < N_CLS; ++c) out[(size_t)i * N_CLS + c] = acc[c];
}

// ---------------------------------------------------------------------------
extern "C" void kernel_launch(void* const* d_in, const int* in_sizes, int n_in,
                              void* d_out, int out_size, void* d_ws, size_t ws_size,
                              hipStream_t stream) {
    const float* x     = (const float*)d_in[0];
    const int*   edge  = (const int*)d_in[1];   // [2, E] int32
    const float* W_emb = (const float*)d_in[2];
    const float* b_emb = (const float*)d_in[3];
    const float* W_gcn = (const float*)d_in[4];
    // d_in[5] = b_gcn: per-feature constant, cancels exactly in BatchNorm -> skip
    const float* gamma = (const float*)d_in[6];
    const float* beta  = (const float*)d_in[7];
    const float* W_cls = (const float*)d_in[8];
    const float* b_cls = (const float*)d_in[9];
    float* out = (float*)d_out;

    // workspace layout (~59 MB)
    float*        h          = (float*)d_ws;                    // N*HID (scaled in place)
    float*        agg        = h + (size_t)N_NODES * HID;       // N*HID
    float*        dis        = agg + (size_t)N_NODES * HID;     // N
    int*          off        = (int*)(dis + N_NODES);           // N+1
    int*          bcnt       = off + N_NODES + 1;               // NB
    int*          boff       = bcnt + NB;                       // NB+1
    int*          bcur       = boff + NB + 1;                   // NB
    unsigned int* binned     = (unsigned int*)(bcur + NB);      // E
    int*          sorted_src = (int*)(binned + N_EDGES);        // E
    float*        stats      = (float*)(sorted_src + N_EDGES);  // 64

    hipMemsetAsync(bcnt, 0, NB * sizeof(int), stream);
    hipMemsetAsync(stats, 0, 64 * sizeof(float), stream);

    const int* src = edge;
    const int* dst = edge + N_EDGES;

    embed_hist_kernel<<<NBLK_EMB + NBLK_H, 256, 0, stream>>>(x, W_emb, b_emb, W_gcn,
                                                             h, dst, bcnt);
    bucket_scan_kernel<<<1, 1024, 0, stream>>>(bcnt, boff, bcur);
    bin_edges_kernel<<<NBLK_BIN, 512, 0, stream>>>(src, dst, bcur, binned);
    bucket_csr_kernel<<<NB, 256, 0, stream>>>(boff, binned, sorted_src, off, h, dis);
    aggregate_kernel<<<(N_NODES * 8 + 255) / 256, 256, 0, stream>>>(off, sorted_src,
                                                                    h, dis, agg);
    stats_kernel<<<1024, 256, 0, stream>>>(agg, stats);
    cls_kernel<<<(N_NODES + 255) / 256, 256, 0, stream>>>(agg, stats, gamma, beta,
                                                          W_cls, b_cls, out);
}

// Round 7
// 151.763 us; speedup vs baseline: 1.4194x; 1.2824x over previous
//
#include <hip/hip_runtime.h>

#define N_NODES 150000
#define N_EDGES 2400000
#define F_IN    22
#define HID     32
#define N_CLS   6
#define BN_EPS  1e-5f

#define BSHIFT  8
#define BMASK   255
#define NB      ((N_NODES + BMASK) >> BSHIFT)       // 586 buckets of 256 nodes
#define CHUNK   8192                                // edges per bin block
#define NBLK_BIN ((N_EDGES + CHUNK - 1) / CHUNK)    // 293 blocks
#define CHUNK_H 8192
#define NBLK_H  ((N_EDGES + CHUNK_H - 1) / CHUNK_H) // 293 hist blocks
#define NBLK_EMB ((N_NODES + 255) / 256)            // 586 embed blocks
#define NREP    8                                   // stats replicas

// ---------------------------------------------------------------------------
// K0 (fused): blocks [0,NBLK_EMB) -> per-node h = relu(x@W_emb+b_emb)@W_gcn
//             blocks [NBLK_EMB, NBLK_EMB+NBLK_H) -> bucket histogram of dst
// ---------------------------------------------------------------------------
__global__ void embed_hist_kernel(const float* __restrict__ x,
                                  const float* __restrict__ W_emb,
                                  const float* __restrict__ b_emb,
                                  const float* __restrict__ W_gcn,
                                  float* __restrict__ h,
                                  const int* __restrict__ dst,
                                  int* __restrict__ bcnt) {
    if (blockIdx.x < NBLK_EMB) {
        __shared__ float sWe[F_IN * HID];
        __shared__ float sbe[HID];
        __shared__ float sWg[HID * HID];
        for (int t = threadIdx.x; t < F_IN * HID; t += blockDim.x) sWe[t] = W_emb[t];
        if (threadIdx.x < HID) sbe[threadIdx.x] = b_emb[threadIdx.x];
        for (int t = threadIdx.x; t < HID * HID; t += blockDim.x) sWg[t] = W_gcn[t];
        __syncthreads();

        int i = blockIdx.x * blockDim.x + threadIdx.x;
        if (i >= N_NODES) return;

        float xi[F_IN];
#pragma unroll
        for (int f = 0; f < F_IN; ++f) xi[f] = x[(size_t)i * F_IN + f];

        float h1[HID];
#pragma unroll
        for (int j = 0; j < HID; ++j) {
            float acc = sbe[j];
#pragma unroll
            for (int f = 0; f < F_IN; ++f) acc = fmaf(xi[f], sWe[f * HID + j], acc);
            h1[j] = fmaxf(acc, 0.0f);
        }
#pragma unroll
        for (int j = 0; j < HID; ++j) {
            float acc = 0.0f;
#pragma unroll
            for (int f = 0; f < HID; ++f) acc = fmaf(h1[f], sWg[f * HID + j], acc);
            h[(size_t)i * HID + j] = acc;
        }
    } else {
        __shared__ int hloc[NB];
        for (int t = threadIdx.x; t < NB; t += 256) hloc[t] = 0;
        __syncthreads();
        int base = (blockIdx.x - NBLK_EMB) * CHUNK_H;
        int end = base + CHUNK_H; if (end > N_EDGES) end = N_EDGES;
        for (int i = base + threadIdx.x; i < end; i += 256)
            atomicAdd(&hloc[dst[i] >> BSHIFT], 1);
        __syncthreads();
        for (int t = threadIdx.x; t < NB; t += 256)
            if (hloc[t]) atomicAdd(&bcnt[t], hloc[t]);
    }
}

// ---------------------------------------------------------------------------
// K1: single-block exclusive scan of NB (=586) bucket counts -> boff, bcur
// ---------------------------------------------------------------------------
__global__ void bucket_scan_kernel(const int* __restrict__ bcnt,
                                   int* __restrict__ boff,
                                   int* __restrict__ bcur) {
    __shared__ int s[1024];
    int t = threadIdx.x;
    int v0 = (t < NB) ? bcnt[t] : 0;
    s[t] = v0;
    __syncthreads();
#pragma unroll
    for (int o = 1; o < 1024; o <<= 1) {
        int v = (t >= o) ? s[t - o] : 0;
        __syncthreads();
        s[t] += v;                 // inclusive
        __syncthreads();
    }
    if (t < NB) {
        int e = s[t] - v0;         // exclusive
        boff[t] = e;
        bcur[t] = e;
    }
    if (t == NB - 1) boff[NB] = s[t];   // == N_EDGES
}

// ---------------------------------------------------------------------------
// K2: binned append, 512 threads. Per block: LDS hist of its 8192-edge chunk
//     -> one global atomic per touched bucket to reserve a range -> packed
//     writes (~56 B runs per (block,bucket)).
//     packed = (dst & 255) << 24 | src   (src < 2^24)
// ---------------------------------------------------------------------------
__global__ void bin_edges_kernel(const int* __restrict__ src,
                                 const int* __restrict__ dst,
                                 int* __restrict__ bcur,
                                 unsigned int* __restrict__ binned) {
    __shared__ int hloc[NB];
    __shared__ int base[NB];
    __shared__ int lcur[NB];
    for (int t = threadIdx.x; t < NB; t += 512) hloc[t] = 0;
    __syncthreads();

    int cbase = blockIdx.x * CHUNK;
    int cend = cbase + CHUNK; if (cend > N_EDGES) cend = N_EDGES;
    for (int i = cbase + threadIdx.x; i < cend; i += 512)
        atomicAdd(&hloc[dst[i] >> BSHIFT], 1);
    __syncthreads();
    for (int t = threadIdx.x; t < NB; t += 512) {
        int c = hloc[t];
        base[t] = c ? atomicAdd(&bcur[t], c) : 0;
        lcur[t] = 0;
    }
    __syncthreads();
    for (int i = cbase + threadIdx.x; i < cend; i += 512) {
        int d = dst[i];
        int b = d >> BSHIFT;
        int r = atomicAdd(&lcur[b], 1);
        binned[base[b] + r] = ((unsigned)(d & BMASK) << 24) | (unsigned)src[i];
    }
}

// ---------------------------------------------------------------------------
// K3: per-bucket local counting sort -> fully dst-sorted sorted_src + off[],
//     plus dis = rsqrt(1+deg).  (h is no longer touched here; dis applied
//     during aggregation.)  Writes stay in this bucket's 16 KB window.
// ---------------------------------------------------------------------------
__global__ void bucket_csr_kernel(const int* __restrict__ boff,
                                  const unsigned int* __restrict__ binned,
                                  int* __restrict__ sorted_src,
                                  int* __restrict__ off,
                                  float* __restrict__ dis) {
    __shared__ int s_cnt[256];
    __shared__ int s_scan[256];
    __shared__ int s_cur[256];
    int b = blockIdx.x;
    int t = threadIdx.x;
    int s0 = boff[b], s1 = boff[b + 1];
    int nbase = b << BSHIFT;
    int nnode = N_NODES - nbase; if (nnode > 256) nnode = 256;

    s_cnt[t] = 0;
    __syncthreads();
    for (int k = s0 + t; k < s1; k += 256)
        atomicAdd(&s_cnt[binned[k] >> 24], 1);
    __syncthreads();

    int v = s_cnt[t];
    s_scan[t] = v;
    __syncthreads();
#pragma unroll
    for (int o = 1; o < 256; o <<= 1) {
        int u = (t >= o) ? s_scan[t - o] : 0;
        __syncthreads();
        s_scan[t] += u;            // inclusive
        __syncthreads();
    }
    int excl = s_scan[t] - v;
    s_cur[t] = excl;
    if (t < nnode) {
        off[nbase + t] = s0 + excl;
        dis[nbase + t] = rsqrtf(1.0f + (float)v);
    }
    if (b == NB - 1 && t == 0) off[N_NODES] = N_EDGES;
    __syncthreads();

    // scatter to node-sorted order (writes stay inside [s0,s1) = 16 KB window)
    for (int k = s0 + t; k < s1; k += 256) {
        unsigned p = binned[k];
        int n = (int)(p >> 24);
        int r = atomicAdd(&s_cur[n], 1);
        sorted_src[s0 + r] = (int)(p & 0xFFFFFFu);
    }
}

// ---------------------------------------------------------------------------
// K4: per-node aggregation + fused BN-stats.  8 threads/node, 4-wide ILP.
//     agg[n] = (h[n]*dis[n] + sum_{in(n)} h[s]*dis[s]) * dis[n]
//     stats accumulated into NREP replica slots to bound atomic contention.
// ---------------------------------------------------------------------------
__global__ void aggregate_kernel(const int* __restrict__ off,
                                 const int* __restrict__ sorted_src,
                                 const float* __restrict__ h,
                                 const float* __restrict__ dis,
                                 float* __restrict__ agg,
                                 float* __restrict__ stats) {
    int t = blockIdx.x * blockDim.x + threadIdx.x;
    int node = t >> 3;
    int c = t & 7;
    bool active = node < N_NODES;

    float4 ps = {0.f, 0.f, 0.f, 0.f};
    float4 pq = {0.f, 0.f, 0.f, 0.f};

    if (active) {
        const float4* hrow = reinterpret_cast<const float4*>(h);
        float dn = dis[node];
        float4 hv = hrow[(size_t)node * 8 + c];
        float4 a0, a1, a2, a3;
        a0.x = hv.x * dn; a0.y = hv.y * dn; a0.z = hv.z * dn; a0.w = hv.w * dn;
        a1 = a2 = a3 = make_float4(0.f, 0.f, 0.f, 0.f);

        int b = off[node], e = off[node + 1];
        int k = b;
        for (; k + 4 <= e; k += 4) {
            int s0 = sorted_src[k], s1 = sorted_src[k + 1];
            int s2 = sorted_src[k + 2], s3 = sorted_src[k + 3];
            float d0 = dis[s0], d1 = dis[s1], d2 = dis[s2], d3 = dis[s3];
            float4 v0 = hrow[(size_t)s0 * 8 + c];
            float4 v1 = hrow[(size_t)s1 * 8 + c];
            float4 v2 = hrow[(size_t)s2 * 8 + c];
            float4 v3 = hrow[(size_t)s3 * 8 + c];
            a0.x = fmaf(v0.x, d0, a0.x); a0.y = fmaf(v0.y, d0, a0.y);
            a0.z = fmaf(v0.z, d0, a0.z); a0.w = fmaf(v0.w, d0, a0.w);
            a1.x = fmaf(v1.x, d1, a1.x); a1.y = fmaf(v1.y, d1, a1.y);
            a1.z = fmaf(v1.z, d1, a1.z); a1.w = fmaf(v1.w, d1, a1.w);
            a2.x = fmaf(v2.x, d2, a2.x); a2.y = fmaf(v2.y, d2, a2.y);
            a2.z = fmaf(v2.z, d2, a2.z); a2.w = fmaf(v2.w, d2, a2.w);
            a3.x = fmaf(v3.x, d3, a3.x); a3.y = fmaf(v3.y, d3, a3.y);
            a3.z = fmaf(v3.z, d3, a3.z); a3.w = fmaf(v3.w, d3, a3.w);
        }
        for (; k < e; ++k) {
            int s = sorted_src[k];
            float d = dis[s];
            float4 v = hrow[(size_t)s * 8 + c];
            a0.x = fmaf(v.x, d, a0.x); a0.y = fmaf(v.y, d, a0.y);
            a0.z = fmaf(v.z, d, a0.z); a0.w = fmaf(v.w, d, a0.w);
        }
        float4 o;
        o.x = (a0.x + a1.x + a2.x + a3.x) * dn;
        o.y = (a0.y + a1.y + a2.y + a3.y) * dn;
        o.z = (a0.z + a1.z + a2.z + a3.z) * dn;
        o.w = (a0.w + a1.w + a2.w + a3.w) * dn;
        reinterpret_cast<float4*>(agg)[(size_t)node * 8 + c] = o;
        ps = o;
        pq.x = o.x * o.x; pq.y = o.y * o.y; pq.z = o.z * o.z; pq.w = o.w * o.w;
    }

    // block-level stats reduce (all 256 threads reach barriers)
    __shared__ float S[256 * 4];
    __shared__ float Q[256 * 4];
    S[threadIdx.x * 4 + 0] = ps.x; S[threadIdx.x * 4 + 1] = ps.y;
    S[threadIdx.x * 4 + 2] = ps.z; S[threadIdx.x * 4 + 3] = ps.w;
    Q[threadIdx.x * 4 + 0] = pq.x; Q[threadIdx.x * 4 + 1] = pq.y;
    Q[threadIdx.x * 4 + 2] = pq.z; Q[threadIdx.x * 4 + 3] = pq.w;
    __syncthreads();
    if (threadIdx.x < 32) {
        int cc = threadIdx.x >> 2, j = threadIdx.x & 3;   // feature f = 4*cc+j
        float s = 0.0f, q = 0.0f;
#pragma unroll
        for (int w = 0; w < 32; ++w) {                    // threads with tid&7==cc
            int tid = (w << 3) | cc;
            s += S[tid * 4 + j];
            q += Q[tid * 4 + j];
        }
        float* rep = stats + 64 * (blockIdx.x & (NREP - 1));
        atomicAdd(&rep[threadIdx.x], s);
        atomicAdd(&rep[32 + threadIdx.x], q);
    }
}

// ---------------------------------------------------------------------------
// K5: out = relu(agg*A + B) @ W_cls + b_cls   (BN fold from NREP stat replicas)
// ---------------------------------------------------------------------------
__global__ void cls_kernel(const float* __restrict__ agg,
                           const float* __restrict__ stats,
                           const float* __restrict__ gamma,
                           const float* __restrict__ beta,
                           const float* __restrict__ W_cls,
                           const float* __restrict__ b_cls,
                           float* __restrict__ out) {
    __shared__ float sA[HID];
    __shared__ float sB[HID];
    __shared__ float sW[HID * N_CLS];
    __shared__ float sb[N_CLS];
    if (threadIdx.x < HID) {
        float sum = 0.0f, sq = 0.0f;
#pragma unroll
        for (int r = 0; r < NREP; ++r) {
            sum += stats[r * 64 + threadIdx.x];
            sq  += stats[r * 64 + 32 + threadIdx.x];
        }
        const float invN = 1.0f / (float)N_NODES;
        float mean = sum * invN;
        float var = sq * invN - mean * mean;
        float inv = rsqrtf(var + BN_EPS);
        float A = gamma[threadIdx.x] * inv;
        sA[threadIdx.x] = A;
        sB[threadIdx.x] = beta[threadIdx.x] - mean * A;
    }
    for (int t = threadIdx.x; t < HID * N_CLS; t += blockDim.x) sW[t] = W_cls[t];
    if (threadIdx.x < N_CLS) sb[threadIdx.x] = b_cls[threadIdx.x];
    __syncthreads();

    int i = blockIdx.x * blockDim.x + threadIdx.x;
    if (i >= N_NODES) return;

    float acc[N_CLS];
#pragma unroll
    for (int c = 0; c < N_CLS; ++c) acc[c] = sb[c];
#pragma unroll
    for (int f = 0; f < HID; ++f) {
        float t = fmaxf(fmaf(agg[(size_t)i * HID + f], sA[f], sB[f]), 0.0f);
#pragma unroll
        for (int c = 0; c < N_CLS; ++c) acc[c] = fmaf(t, sW[f * N_CLS + c], acc[c]);
    }
#pragma unroll
    for (int c = 0; c < N_CLS; ++c) out[(size_t)i * N_CLS + c] = acc[c];
}

// ---------------------------------------------------------------------------
extern "C" void kernel_launch(void* const* d_in, const int* in_sizes, int n_in,
                              void* d_out, int out_size, void* d_ws, size_t ws_size,
                              hipStream_t stream) {
    const float* x     = (const float*)d_in[0];
    const int*   edge  = (const int*)d_in[1];   // [2, E] int32
    const float* W_emb = (const float*)d_in[2];
    const float* b_emb = (const float*)d_in[3];
    const float* W_gcn = (const float*)d_in[4];
    // d_in[5] = b_gcn: per-feature constant, cancels exactly in BatchNorm -> skip
    const float* gamma = (const float*)d_in[6];
    const float* beta  = (const float*)d_in[7];
    const float* W_cls = (const float*)d_in[8];
    const float* b_cls = (const float*)d_in[9];
    float* out = (float*)d_out;

    // workspace layout (~59 MB)
    float*        h          = (float*)d_ws;                    // N*HID (unscaled)
    float*        agg        = h + (size_t)N_NODES * HID;       // N*HID
    float*        dis        = agg + (size_t)N_NODES * HID;     // N
    int*          off        = (int*)(dis + N_NODES);           // N+1
    int*          bcnt       = off + N_NODES + 1;               // NB
    int*          boff       = bcnt + NB;                       // NB+1
    int*          bcur       = boff + NB + 1;                   // NB
    unsigned int* binned     = (unsigned int*)(bcur + NB);      // E
    int*          sorted_src = (int*)(binned + N_EDGES);        // E
    float*        stats      = (float*)(sorted_src + N_EDGES);  // 64*NREP

    hipMemsetAsync(bcnt, 0, NB * sizeof(int), stream);
    hipMemsetAsync(stats, 0, 64 * NREP * sizeof(float), stream);

    const int* src = edge;
    const int* dst = edge + N_EDGES;

    embed_hist_kernel<<<NBLK_EMB + NBLK_H, 256, 0, stream>>>(x, W_emb, b_emb, W_gcn,
                                                             h, dst, bcnt);
    bucket_scan_kernel<<<1, 1024, 0, stream>>>(bcnt, boff, bcur);
    bin_edges_kernel<<<NBLK_BIN, 512, 0, stream>>>(src, dst, bcur, binned);
    bucket_csr_kernel<<<NB, 256, 0, stream>>>(boff, binned, sorted_src, off, dis);
    aggregate_kernel<<<(N_NODES * 8 + 255) / 256, 256, 0, stream>>>(off, sorted_src,
                                                                    h, dis, agg, stats);
    cls_kernel<<<(N_NODES + 255) / 256, 256, 0, stream>>>(agg, stats, gamma, beta,
                                                          W_cls, b_cls, out);
}